// Round 21
// baseline (75.259 us; speedup 1.0000x reference)
//
#include <hip/hip_runtime.h>

#define T_IN 1024
#define D_DIM 512
#define T_OUT 1280
#define NPAIR 4096   // 8 * 512

// ---------------------------------------------------------------------------
// K1: transpose (b, t, d) -> (b, d, t), 64x64 LDS tiles.
// Builds fp64 tw[m] = (cos, -sin)(2 pi m/1024), fp32 sixteenth table
// tw16f[0..64] = (cos, sin), and fp32 w32f[j] = (cos, -sin)(2 pi j/32).
// ---------------------------------------------------------------------------
__global__ __launch_bounds__(256) void transpose_kernel(const float* __restrict__ x,
                                                        float* __restrict__ xt,
                                                        double2* __restrict__ tw,
                                                        float2* __restrict__ tw16f,
                                                        float2* __restrict__ w32f) {
    __shared__ float tile[64][65];
    const int b  = blockIdx.z;
    const int t0 = blockIdx.y * 64;
    const int d0 = blockIdx.x * 64;
    const int dl = threadIdx.x & 63;
    const int r0 = threadIdx.x >> 6;   // 0..3

    if (blockIdx.x < 4 && blockIdx.y == 0 && blockIdx.z == 0) {
        int m = blockIdx.x * 256 + threadIdx.x;
        double th = (6.283185307179586476925286766559 / 1024.0) * (double)m;
        double c = cos(th), s = sin(th);
        tw[m] = make_double2(c, -s);
        if (m <= 64)       tw16f[m]      = make_float2((float)c, (float)s);
        if ((m & 31) == 0) w32f[m >> 5]  = make_float2((float)c, (float)(-s));
    }

#pragma unroll
    for (int i = 0; i < 16; ++i) {
        int tl = r0 * 16 + i;
        tile[tl][dl] = x[((size_t)b * T_IN + (t0 + tl)) * D_DIM + d0 + dl];
    }
    __syncthreads();
#pragma unroll
    for (int i = 0; i < 16; ++i) {
        int dl2 = r0 * 16 + i;
        xt[((size_t)b * D_DIM + (d0 + dl2)) * T_IN + t0 + dl] = tile[dl][dl2];
    }
}

// ---------------------------------------------------------------------------
// sixteenth-table twiddle lookup, fp64 (fallback kernel)
// ---------------------------------------------------------------------------
__device__ __forceinline__ double2 TW16(const double2* __restrict__ E, int m) {
    const double RS2 = 0.70710678118654752440084436210485;
    int r = m & 255;
    int q = (m >> 8) & 3;
    int r2 = (r <= 128) ? r : 256 - r;
    double cc, ss;
    if (r2 <= 64) {
        double2 t = E[r2];
        cc = t.x; ss = t.y;
    } else {
        double2 t = E[128 - r2];
        cc = (t.x + t.y) * RS2;
        ss = (t.x - t.y) * RS2;
    }
    double c, s;
    if (r > 128) { c = ss; s = cc; } else { c = cc; s = ss; }
    double C, S;
    switch (q) {
        case 0:  C = c;  S = s;  break;
        case 1:  C = -s; S = c;  break;
        case 2:  C = -c; S = -s; break;
        default: C = s;  S = -c; break;
    }
    return make_double2(C, -S);
}

// fp32 version
__device__ __forceinline__ float2 TW16F(const float2* __restrict__ E, int m) {
    const float RS2 = 0.70710678118654752440f;
    int r = m & 255;
    int q = (m >> 8) & 3;
    int r2 = (r <= 128) ? r : 256 - r;
    float cc, ss;
    if (r2 <= 64) {
        float2 t = E[r2];
        cc = t.x; ss = t.y;
    } else {
        float2 t = E[128 - r2];
        cc = (t.x + t.y) * RS2;
        ss = (t.x - t.y) * RS2;
    }
    float c, s;
    if (r > 128) { c = ss; s = cc; } else { c = cc; s = ss; }
    float C, S;
    switch (q) {
        case 0:  C = c;  S = s;  break;
        case 1:  C = -s; S = c;  break;
        case 2:  C = -c; S = -s; break;
        default: C = s;  S = -c; break;
    }
    return make_float2(C, -S);
}

// ---------------------------------------------------------------------------
// K2a (fp32): full pipeline in fp32 with margin certification.
// Writes sel for all pairs and flag[pair]=1 when the fp32 selection margin
// (rank32 - rank33 of amp^2) is < 1e-3 relative -> fp64 fallback re-does it.
// ---------------------------------------------------------------------------
__global__ __launch_bounds__(256) void dft32_kernel(const float* __restrict__ xt,
                                                    const float2* __restrict__ tw16fg,
                                                    const float2* __restrict__ w32fg,
                                                    float2* __restrict__ stats,
                                                    float4* __restrict__ sel,
                                                    int* __restrict__ flag) {
    __shared__ float2 uni[1024];        // A: xs float[1024] (4KB); B: E [32][32]
                                        // (8KB); C: spec float2[512] (4KB) +
                                        // cand ull[132] @byte 4096
    __shared__ float2 tw_s[65];         // fp32 sixteenth table
    __shared__ float2 w32_s[32];        // fp32 W32 table
    __shared__ double red_s[16];
    float* xs_f = (float*)uni;

    const int tid  = threadIdx.x;
    const int pair = blockIdx.x;

    const float4 v = reinterpret_cast<const float4*>(xt + (size_t)pair * T_IN)[tid];

    if (tid < 65) tw_s[tid] = tw16fg[tid];
    if (tid >= 128 && tid < 160) w32_s[tid - 128] = w32fg[tid - 128];

    // --- stats in fp64 (identical to fallback path) ---
    double sum = (double)v.x + (double)v.y + (double)v.z + (double)v.w;
    double sq  = (double)v.x * v.x + (double)v.y * v.y +
                 (double)v.z * v.z + (double)v.w * v.w;
#pragma unroll
    for (int off = 32; off; off >>= 1) {
        sum += __shfl_down(sum, off);
        sq  += __shfl_down(sq, off);
    }
    const int wv   = tid >> 6;
    const int lane = tid & 63;
    if (lane == 0) { red_s[wv] = sum; red_s[8 + wv] = sq; }
    __syncthreads();
    double mean, stdp;
    {
        double s = red_s[0] + red_s[1] + red_s[2] + red_s[3];
        double q = red_s[8] + red_s[9] + red_s[10] + red_s[11];
        mean = s * (1.0 / 1024.0);
        double var = (q - 1024.0 * mean * mean) * (1.0 / 1023.0);
        var = var > 0.0 ? var : 0.0;
        stdp = sqrt(var) + 1e-8;
        if (tid == 0) stats[pair] = make_float2((float)mean, (float)stdp);
    }
    const double inv = 1.0 / stdp;
    {
        double z0 = ((double)v.x - mean) * inv;
        double z1 = ((double)v.y - mean) * inv;
        double z2 = ((double)v.z - mean) * inv;
        double z3 = ((double)v.w - mean) * inv;
        z0 = fmin(2.0, fmax(-2.0, z0)) + 1e-9;
        z1 = fmin(2.0, fmax(-2.0, z1)) + 1e-9;
        z2 = fmin(2.0, fmax(-2.0, z2)) + 1e-9;
        z3 = fmin(2.0, fmax(-2.0, z3)) + 1e-9;
        xs_f[tid * 4 + 0] = (float)z0;
        xs_f[tid * 4 + 1] = (float)z1;
        xs_f[tid * 4 + 2] = (float)z2;
        xs_f[tid * 4 + 3] = (float)z3;
    }
    __syncthreads();

    // --- even/odd butterfly (fp32) ---
    {
        int idx = tid;
#pragma unroll
        for (int rr = 0; rr < 2; ++rr) {
            if (idx < 480) {
                int t1p = 1 + (idx >> 5);
                int t2c = idx & 31;
                int ia = t1p * 32 + t2c;
                int ib = (32 - t1p) * 32 + t2c;
                float a = xs_f[ia], b = xs_f[ib];
                xs_f[ia] = a + b;
                xs_f[ib] = a - b;
            }
            idx += 256;
        }
    }
    __syncthreads();

    const int k1 = tid & 31;
    const int g  = tid >> 5;

    // --- stage 1 (fp32, W32-table rotators) ---
    float2 R0, R1, R2, R3;
    {
        const float sgn16 = (k1 & 1) ? -1.0f : 1.0f;

        float ar0 = xs_f[g]      + sgn16 * xs_f[512 + g];
        float ar1 = xs_f[g + 8]  + sgn16 * xs_f[512 + g + 8];
        float ar2 = xs_f[g + 16] + sgn16 * xs_f[512 + g + 16];
        float ar3 = xs_f[g + 24] + sgn16 * xs_f[512 + g + 24];
        float ai0 = 0, ai1 = 0, ai2 = 0, ai3 = 0;

        int jw = 0;
#pragma unroll 5
        for (int t1 = 1; t1 <= 15; ++t1) {
            jw = (jw + k1) & 31;
            float2 w = w32_s[jw];
            const float* eb = &xs_f[t1 * 32];
            const float* ob = &xs_f[(32 - t1) * 32];
            ar0 = fmaf(eb[g], w.x, ar0);      ai0 = fmaf(ob[g], w.y, ai0);
            ar1 = fmaf(eb[g + 8], w.x, ar1);  ai1 = fmaf(ob[g + 8], w.y, ai1);
            ar2 = fmaf(eb[g + 16], w.x, ar2); ai2 = fmaf(ob[g + 16], w.y, ai2);
            ar3 = fmaf(eb[g + 24], w.x, ar3); ai3 = fmaf(ob[g + 24], w.y, ai3);
        }
        {
            float2 tm = TW16F(tw_s, g * k1);
            R0 = make_float2(ar0 * tm.x - ai0 * tm.y, ar0 * tm.y + ai0 * tm.x);
        }
        {
            float2 tm = TW16F(tw_s, (g + 8) * k1);
            R1 = make_float2(ar1 * tm.x - ai1 * tm.y, ar1 * tm.y + ai1 * tm.x);
        }
        {
            float2 tm = TW16F(tw_s, (g + 16) * k1);
            R2 = make_float2(ar2 * tm.x - ai2 * tm.y, ar2 * tm.y + ai2 * tm.x);
        }
        {
            float2 tm = TW16F(tw_s, (g + 24) * k1);
            R3 = make_float2(ar3 * tm.x - ai3 * tm.y, ar3 * tm.y + ai3 * tm.x);
        }
    }
    __syncthreads();

    // fold-at-write: E+ rows 0..15, E- rows 16..31
    uni[g * 32 + k1]        = make_float2(R0.x + R2.x, R0.y + R2.y);
    uni[(g + 16) * 32 + k1] = make_float2(R0.x - R2.x, R0.y - R2.y);
    uni[(g + 8) * 32 + k1]  = make_float2(R1.x + R3.x, R1.y + R3.y);
    uni[(g + 24) * 32 + k1] = make_float2(R1.x - R3.x, R1.y - R3.y);
    __syncthreads();

    // --- stage 2 (fp32) ---
    float Ar = 0, Ai = 0, Br = 0, Bi = 0;
    {
        const int ebase = (g & 1) ? 16 * 32 : 0;
        int ja = 0;
#pragma unroll
        for (int u = 0; u < 4; ++u) {
            {
                float2 w = w32_s[ja]; ja = (ja + g) & 31;
                float2 E = uni[ebase + (4 * u + 0) * 32 + k1];
                float P = fmaf(E.x, w.x, -(E.y * w.y));
                float Q = fmaf(E.x, w.y,  (E.y * w.x));
                Ar += P; Ai += Q; Br += P; Bi += Q;
            }
            {
                float2 w = w32_s[ja]; ja = (ja + g) & 31;
                float2 E = uni[ebase + (4 * u + 1) * 32 + k1];
                float P = fmaf(E.x, w.x, -(E.y * w.y));
                float Q = fmaf(E.x, w.y,  (E.y * w.x));
                Ar += P; Ai += Q; Br += Q; Bi -= P;
            }
            {
                float2 w = w32_s[ja]; ja = (ja + g) & 31;
                float2 E = uni[ebase + (4 * u + 2) * 32 + k1];
                float P = fmaf(E.x, w.x, -(E.y * w.y));
                float Q = fmaf(E.x, w.y,  (E.y * w.x));
                Ar += P; Ai += Q; Br -= P; Bi -= Q;
            }
            {
                float2 w = w32_s[ja]; ja = (ja + g) & 31;
                float2 E = uni[ebase + (4 * u + 3) * 32 + k1];
                float P = fmaf(E.x, w.x, -(E.y * w.y));
                float Q = fmaf(E.x, w.y,  (E.y * w.x));
                Ar += P; Ai += Q; Br -= Q; Bi += P;
            }
        }
    }
    const int ka = k1 + 32 * g;
    const int kb = ka + 256;

    // keys: hi32 = fp32 amp^2 bits (monotone for >=0), lo32 = 1023-k tiebreak
    unsigned long long uA, uB;
    {
        float a2a = Ar * Ar + Ai * Ai;
        float a2b = Br * Br + Bi * Bi;
        uA = ((unsigned long long)__float_as_uint(a2a) << 32) |
             (unsigned int)(1023 - ka);
        uB = ((unsigned long long)__float_as_uint(a2b) << 32) |
             (unsigned int)(1023 - kb);
        if (ka == 0) uA = 0;   // DC excluded
    }

    __syncthreads();
    float2* spec_f = (float2*)uni;                       // bytes [0, 4K)
    unsigned long long* cand = (unsigned long long*)(uni + 512);   // [4K, 5.1K)
    spec_f[ka] = make_float2(Ar, Ai);
    spec_f[kb] = make_float2(Br, Bi);

    const unsigned long long lt = lane ? (0xFFFFFFFFFFFFFFFFULL >> (64 - lane))
                                       : 0ULL;

    // --- phase A: per-wave TOP-33 (guarantees global rank-33 in candidates) ---
    {
        const unsigned int aHi = (unsigned int)(uA >> 32);
        const unsigned int bHi = (unsigned int)(uB >> 32);
        unsigned int pref = 0;
#pragma unroll
        for (int bit = 31; bit >= 0; --bit) {
            unsigned int trial = pref | (1u << bit);
            int cnt = __popcll(__ballot(aHi >= trial)) +
                      __popcll(__ballot(bHi >= trial));
            if (cnt >= 33) pref = trial;
        }
        unsigned long long gA = __ballot(aHi > pref);
        unsigned long long gB = __ballot(bHi > pref);
        unsigned long long eA = __ballot(aHi == pref);
        unsigned long long eB = __ballot(bHi == pref);
        int nH = __popcll(gA) + __popcll(gB);
        int nE = __popcll(eA) + __popcll(eB);
        bool winA, winB;
        if (nH + nE == 33) {
            winA = (aHi >= pref);
            winB = (bHi >= pref);
        } else {   // hi ties: exact resolve on lo32 (distinct index bits)
            const unsigned int aLo = (unsigned int)uA;
            const unsigned int bLo = (unsigned int)uB;
            int need = 33 - nH;
            unsigned int lp = 0;
            for (int bit = 31; bit >= 0; --bit) {
                unsigned int t = lp | (1u << bit);
                int c = __popcll(__ballot((aHi == pref) && (aLo >= t))) +
                        __popcll(__ballot((bHi == pref) && (bLo >= t)));
                if (c >= need) lp = t;
            }
            winA = (aHi > pref) || ((aHi == pref) && (aLo >= lp));
            winB = (bHi > pref) || ((bHi == pref) && (bLo >= lp));
        }
        unsigned long long mA = __ballot(winA);
        unsigned long long mB = __ballot(winB);
        const int bs = wv * 33;
        if (winA) cand[bs + __popcll(mA & lt)] = uA;
        if (winB) cand[bs + __popcll(mA) + __popcll(mB & lt)] = uB;
    }
    __syncthreads();

    // --- phase B: wave 0, top-32 of 132 candidates + margin ---
    if (tid < 64) {
        unsigned long long c0 = cand[tid];
        unsigned long long c1 = cand[tid + 64];
        unsigned long long c2 = (tid < 4) ? cand[128 + tid] : 0ULL;
        const unsigned int h0 = (unsigned int)(c0 >> 32);
        const unsigned int h1 = (unsigned int)(c1 >> 32);
        const unsigned int h2 = (unsigned int)(c2 >> 32);
        unsigned int pref = 0;
#pragma unroll
        for (int bit = 31; bit >= 0; --bit) {
            unsigned int trial = pref | (1u << bit);
            int cnt = __popcll(__ballot(h0 >= trial)) +
                      __popcll(__ballot(h1 >= trial)) +
                      __popcll(__ballot(h2 >= trial));
            if (cnt >= 32) pref = trial;
        }
        unsigned long long g0 = __ballot(h0 > pref);
        unsigned long long g1 = __ballot(h1 > pref);
        unsigned long long g2 = __ballot(h2 > pref);
        unsigned long long e0 = __ballot(h0 == pref);
        unsigned long long e1 = __ballot(h1 == pref);
        unsigned long long e2 = __ballot(h2 == pref);
        int nH = __popcll(g0) + __popcll(g1) + __popcll(g2);
        int nE = __popcll(e0) + __popcll(e1) + __popcll(e2);
        bool win0, win1, win2;
        if (nH + nE == 32) {
            win0 = (h0 >= pref);
            win1 = (h1 >= pref);
            win2 = (h2 >= pref);
        } else {
            const unsigned int l0 = (unsigned int)c0;
            const unsigned int l1 = (unsigned int)c1;
            const unsigned int l2 = (unsigned int)c2;
            int need = 32 - nH;
            unsigned int lp = 0;
            for (int bit = 31; bit >= 0; --bit) {
                unsigned int t = lp | (1u << bit);
                int c = __popcll(__ballot((h0 == pref) && (l0 >= t))) +
                        __popcll(__ballot((h1 == pref) && (l1 >= t))) +
                        __popcll(__ballot((h2 == pref) && (l2 >= t)));
                if (c >= need) lp = t;
            }
            win0 = (h0 > pref) || ((h0 == pref) && (l0 >= lp));
            win1 = (h1 > pref) || ((h1 == pref) && (l1 >= lp));
            win2 = (h2 > pref) || ((h2 == pref) && (l2 >= lp));
        }
        // margin: min winner amp^2 vs max loser amp^2 (rank-33 is a candidate)
        float minW = 3.4e38f, maxL = 0.0f;
        {
            float a2 = __uint_as_float(h0);
            if (win0) minW = fminf(minW, a2); else maxL = fmaxf(maxL, a2);
        }
        {
            float a2 = __uint_as_float(h1);
            if (win1) minW = fminf(minW, a2); else maxL = fmaxf(maxL, a2);
        }
        {
            float a2 = __uint_as_float(h2);
            if (win2) minW = fminf(minW, a2); else maxL = fmaxf(maxL, a2);
        }
#pragma unroll
        for (int off = 1; off < 64; off <<= 1) {
            minW = fminf(minW, __shfl_xor(minW, off));
            maxL = fmaxf(maxL, __shfl_xor(maxL, off));
        }
        if (tid == 0)
            flag[pair] = ((minW - maxL) < 1e-3f * minW) ? 1 : 0;

        unsigned long long m0 = __ballot(win0);
        unsigned long long m1 = __ballot(win1);
        unsigned long long m2 = __ballot(win2);
        const float C = 6.28318530717958647692f / 1024.0f;
        const size_t sb = (size_t)pair * 32;
        if (win0) {
            int slot = __popcll(m0 & lt);
            int k = 1023 - (int)(c0 & 0xFFFFFFFFULL);
            float2 sp = spec_f[k];
            float ph = atan2f(sp.y, sp.x);
            float aout = 2.0f * sqrtf(__uint_as_float(h0)) * (1.0f / 1024.0f);
            float tkc = __cosf((float)k * C);
            sel[sb + slot] = make_float4(aout, ph, (float)k, tkc);
        }
        if (win1) {
            int slot = __popcll(m0) + __popcll(m1 & lt);
            int k = 1023 - (int)(c1 & 0xFFFFFFFFULL);
            float2 sp = spec_f[k];
            float ph = atan2f(sp.y, sp.x);
            float aout = 2.0f * sqrtf(__uint_as_float(h1)) * (1.0f / 1024.0f);
            float tkc = __cosf((float)k * C);
            sel[sb + slot] = make_float4(aout, ph, (float)k, tkc);
        }
        if (win2) {
            int slot = __popcll(m0) + __popcll(m1) + __popcll(m2 & lt);
            int k = 1023 - (int)(c2 & 0xFFFFFFFFULL);
            float2 sp = spec_f[k];
            float ph = atan2f(sp.y, sp.x);
            float aout = 2.0f * sqrtf(__uint_as_float(h2)) * (1.0f / 1024.0f);
            float tkc = __cosf((float)k * C);
            sel[sb + slot] = make_float4(aout, ph, (float)k, tkc);
        }
    }
}

// ---------------------------------------------------------------------------
// K2b (fp64 fallback, r20-proven): re-does flagged pairs only.
// ---------------------------------------------------------------------------
__global__ __launch_bounds__(256) void dft64_kernel(const float* __restrict__ xt,
                                                    const double2* __restrict__ twg,
                                                    float2* __restrict__ stats,
                                                    float4* __restrict__ sel,
                                                    const int* __restrict__ flag) {
    const int pair = blockIdx.x;
    if (flag[pair] == 0) return;   // uniform per block, before any barrier

    __shared__ double2 uni[1024];
    __shared__ double2 tw_s[65];
    __shared__ double2 w32_s[32];
    __shared__ double  red_s[16];
    double* xs_s = (double*)uni;

    const int tid  = threadIdx.x;

    const float4 v = reinterpret_cast<const float4*>(xt + (size_t)pair * T_IN)[tid];

    if (tid < 65) {
        double2 t = twg[tid];
        tw_s[tid] = make_double2(t.x, -t.y);
    }
    if (tid >= 128 && tid < 160) {
        w32_s[tid - 128] = twg[(tid - 128) * 32];
    }

    double sum = (double)v.x + (double)v.y + (double)v.z + (double)v.w;
    double sq  = (double)v.x * v.x + (double)v.y * v.y +
                 (double)v.z * v.z + (double)v.w * v.w;
#pragma unroll
    for (int off = 32; off; off >>= 1) {
        sum += __shfl_down(sum, off);
        sq  += __shfl_down(sq, off);
    }
    const int wv   = tid >> 6;
    const int lane = tid & 63;
    if (lane == 0) { red_s[wv] = sum; red_s[8 + wv] = sq; }
    __syncthreads();
    double mean, stdp;
    {
        double s = red_s[0] + red_s[1] + red_s[2] + red_s[3];
        double q = red_s[8] + red_s[9] + red_s[10] + red_s[11];
        mean = s * (1.0 / 1024.0);
        double var = (q - 1024.0 * mean * mean) * (1.0 / 1023.0);
        var = var > 0.0 ? var : 0.0;
        stdp = sqrt(var) + 1e-8;
        if (tid == 0) stats[pair] = make_float2((float)mean, (float)stdp);
    }
    const double inv = 1.0 / stdp;
    {
        double z0 = ((double)v.x - mean) * inv;
        double z1 = ((double)v.y - mean) * inv;
        double z2 = ((double)v.z - mean) * inv;
        double z3 = ((double)v.w - mean) * inv;
        z0 = fmin(2.0, fmax(-2.0, z0)) + 1e-9;
        z1 = fmin(2.0, fmax(-2.0, z1)) + 1e-9;
        z2 = fmin(2.0, fmax(-2.0, z2)) + 1e-9;
        z3 = fmin(2.0, fmax(-2.0, z3)) + 1e-9;
        xs_s[tid * 4 + 0] = z0;
        xs_s[tid * 4 + 1] = z1;
        xs_s[tid * 4 + 2] = z2;
        xs_s[tid * 4 + 3] = z3;
    }
    __syncthreads();

    {
        int idx = tid;
#pragma unroll
        for (int rr = 0; rr < 2; ++rr) {
            if (idx < 480) {
                int t1p = 1 + (idx >> 5);
                int t2c = idx & 31;
                int ia = t1p * 32 + t2c;
                int ib = (32 - t1p) * 32 + t2c;
                double a = xs_s[ia], b = xs_s[ib];
                xs_s[ia] = a + b;
                xs_s[ib] = a - b;
            }
            idx += 256;
        }
    }
    __syncthreads();

    const int k1 = tid & 31;
    const int g  = tid >> 5;

    double2 R0, R1, R2, R3;
    {
        const double sgn16 = (k1 & 1) ? -1.0 : 1.0;

        double ar0 = xs_s[g]      + sgn16 * xs_s[512 + g];
        double ar1 = xs_s[g + 8]  + sgn16 * xs_s[512 + g + 8];
        double ar2 = xs_s[g + 16] + sgn16 * xs_s[512 + g + 16];
        double ar3 = xs_s[g + 24] + sgn16 * xs_s[512 + g + 24];
        double ai0 = 0, ai1 = 0, ai2 = 0, ai3 = 0;

        int jw = 0;
#pragma unroll 5
        for (int t1 = 1; t1 <= 15; ++t1) {
            jw = (jw + k1) & 31;
            double2 w = w32_s[jw];
            const double* eb = &xs_s[t1 * 32];
            const double* ob = &xs_s[(32 - t1) * 32];
            ar0 = fma(eb[g], w.x, ar0);      ai0 = fma(ob[g], w.y, ai0);
            ar1 = fma(eb[g + 8], w.x, ar1);  ai1 = fma(ob[g + 8], w.y, ai1);
            ar2 = fma(eb[g + 16], w.x, ar2); ai2 = fma(ob[g + 16], w.y, ai2);
            ar3 = fma(eb[g + 24], w.x, ar3); ai3 = fma(ob[g + 24], w.y, ai3);
        }
        {
            double2 tm = TW16(tw_s, g * k1);
            R0 = make_double2(ar0 * tm.x - ai0 * tm.y, ar0 * tm.y + ai0 * tm.x);
        }
        {
            double2 tm = TW16(tw_s, (g + 8) * k1);
            R1 = make_double2(ar1 * tm.x - ai1 * tm.y, ar1 * tm.y + ai1 * tm.x);
        }
        {
            double2 tm = TW16(tw_s, (g + 16) * k1);
            R2 = make_double2(ar2 * tm.x - ai2 * tm.y, ar2 * tm.y + ai2 * tm.x);
        }
        {
            double2 tm = TW16(tw_s, (g + 24) * k1);
            R3 = make_double2(ar3 * tm.x - ai3 * tm.y, ar3 * tm.y + ai3 * tm.x);
        }
    }
    __syncthreads();

    uni[g * 32 + k1]        = make_double2(R0.x + R2.x, R0.y + R2.y);
    uni[(g + 16) * 32 + k1] = make_double2(R0.x - R2.x, R0.y - R2.y);
    uni[(g + 8) * 32 + k1]  = make_double2(R1.x + R3.x, R1.y + R3.y);
    uni[(g + 24) * 32 + k1] = make_double2(R1.x - R3.x, R1.y - R3.y);
    __syncthreads();

    double Ar = 0, Ai = 0, Br = 0, Bi = 0;
    {
        const int ebase = (g & 1) ? 16 * 32 : 0;
        int ja = 0;
#pragma unroll
        for (int u = 0; u < 4; ++u) {
            {
                double2 w = w32_s[ja]; ja = (ja + g) & 31;
                double2 E = uni[ebase + (4 * u + 0) * 32 + k1];
                double P = fma(E.x, w.x, -(E.y * w.y));
                double Q = fma(E.x, w.y,  (E.y * w.x));
                Ar += P; Ai += Q; Br += P; Bi += Q;
            }
            {
                double2 w = w32_s[ja]; ja = (ja + g) & 31;
                double2 E = uni[ebase + (4 * u + 1) * 32 + k1];
                double P = fma(E.x, w.x, -(E.y * w.y));
                double Q = fma(E.x, w.y,  (E.y * w.x));
                Ar += P; Ai += Q; Br += Q; Bi -= P;
            }
            {
                double2 w = w32_s[ja]; ja = (ja + g) & 31;
                double2 E = uni[ebase + (4 * u + 2) * 32 + k1];
                double P = fma(E.x, w.x, -(E.y * w.y));
                double Q = fma(E.x, w.y,  (E.y * w.x));
                Ar += P; Ai += Q; Br -= P; Bi -= Q;
            }
            {
                double2 w = w32_s[ja]; ja = (ja + g) & 31;
                double2 E = uni[ebase + (4 * u + 3) * 32 + k1];
                double P = fma(E.x, w.x, -(E.y * w.y));
                double Q = fma(E.x, w.y,  (E.y * w.x));
                Ar += P; Ai += Q; Br -= Q; Bi += P;
            }
        }
    }
    const int ka = k1 + 32 * g;
    const int kb = ka + 256;

    unsigned long long uA, uB;
    {
        double a2a = Ar * Ar + Ai * Ai;
        double a2b = Br * Br + Bi * Bi;
        unsigned long long bba = __double_as_longlong(a2a);
        unsigned long long bbb = __double_as_longlong(a2b);
        double keya = __longlong_as_double((bba & ~1023ULL) |
                                           (unsigned long long)(1023 - ka));
        double keyb = __longlong_as_double((bbb & ~1023ULL) |
                                           (unsigned long long)(1023 - kb));
        if (ka == 0) keya = -1.0;
        unsigned long long a = (unsigned long long)__double_as_longlong(keya);
        unsigned long long b = (unsigned long long)__double_as_longlong(keyb);
        uA = a ^ ((a >> 63) ? 0xFFFFFFFFFFFFFFFFULL : 0x8000000000000000ULL);
        uB = b ^ ((b >> 63) ? 0xFFFFFFFFFFFFFFFFULL : 0x8000000000000000ULL);
    }

    __syncthreads();
    float2* spec_f = (float2*)uni;
    double* cand   = (double*)(uni + 512);
    spec_f[ka] = make_float2((float)Ar, (float)Ai);
    spec_f[kb] = make_float2((float)Br, (float)Bi);

    const unsigned long long lt = lane ? (0xFFFFFFFFFFFFFFFFULL >> (64 - lane))
                                       : 0ULL;

    {
        const unsigned int aHi = (unsigned int)(uA >> 32);
        const unsigned int bHi = (unsigned int)(uB >> 32);
        unsigned int pref = 0x80000000u;
#pragma unroll
        for (int bit = 30; bit >= 0; --bit) {
            unsigned int trial = pref | (1u << bit);
            int cnt = __popcll(__ballot(aHi >= trial)) +
                      __popcll(__ballot(bHi >= trial));
            if (cnt >= 32) pref = trial;
        }
        unsigned long long gA = __ballot(aHi > pref);
        unsigned long long gB = __ballot(bHi > pref);
        unsigned long long eA = __ballot(aHi == pref);
        unsigned long long eB = __ballot(bHi == pref);
        int nH = __popcll(gA) + __popcll(gB);
        int nE = __popcll(eA) + __popcll(eB);
        bool winA, winB;
        if (nH + nE == 32) {
            winA = (aHi >= pref);
            winB = (bHi >= pref);
        } else {
            const unsigned int aLo = (unsigned int)uA;
            const unsigned int bLo = (unsigned int)uB;
            int need = 32 - nH;
            unsigned int lp = 0;
            for (int bit = 31; bit >= 0; --bit) {
                unsigned int t = lp | (1u << bit);
                int c = __popcll(__ballot((aHi == pref) && (aLo >= t))) +
                        __popcll(__ballot((bHi == pref) && (bLo >= t)));
                if (c >= need) lp = t;
            }
            winA = (aHi > pref) || ((aHi == pref) && (aLo >= lp));
            winB = (bHi > pref) || ((bHi == pref) && (bLo >= lp));
        }
        unsigned long long mA = __ballot(winA);
        unsigned long long mB = __ballot(winB);
        const int bs = wv * 32;
        if (winA)
            cand[bs + __popcll(mA & lt)] = __longlong_as_double((long long)uA);
        if (winB)
            cand[bs + __popcll(mA) + __popcll(mB & lt)] =
                __longlong_as_double((long long)uB);
    }
    __syncthreads();

    if (tid < 64) {
        unsigned long long c0 =
            (unsigned long long)__double_as_longlong(cand[tid]);
        unsigned long long c1 =
            (unsigned long long)__double_as_longlong(cand[tid + 64]);
        const unsigned int h0 = (unsigned int)(c0 >> 32);
        const unsigned int h1 = (unsigned int)(c1 >> 32);
        unsigned int pref = 0x80000000u;
#pragma unroll
        for (int bit = 30; bit >= 0; --bit) {
            unsigned int trial = pref | (1u << bit);
            int cnt = __popcll(__ballot(h0 >= trial)) +
                      __popcll(__ballot(h1 >= trial));
            if (cnt >= 32) pref = trial;
        }
        unsigned long long g0 = __ballot(h0 > pref);
        unsigned long long g1 = __ballot(h1 > pref);
        unsigned long long e0 = __ballot(h0 == pref);
        unsigned long long e1 = __ballot(h1 == pref);
        int nH = __popcll(g0) + __popcll(g1);
        int nE = __popcll(e0) + __popcll(e1);
        bool win0, win1;
        if (nH + nE == 32) {
            win0 = (h0 >= pref);
            win1 = (h1 >= pref);
        } else {
            const unsigned int l0 = (unsigned int)c0;
            const unsigned int l1 = (unsigned int)c1;
            int need = 32 - nH;
            unsigned int lp = 0;
            for (int bit = 31; bit >= 0; --bit) {
                unsigned int t = lp | (1u << bit);
                int c = __popcll(__ballot((h0 == pref) && (l0 >= t))) +
                        __popcll(__ballot((h1 == pref) && (l1 >= t)));
                if (c >= need) lp = t;
            }
            win0 = (h0 > pref) || ((h0 == pref) && (l0 >= lp));
            win1 = (h1 > pref) || ((h1 == pref) && (l1 >= lp));
        }
        unsigned long long m0 = __ballot(win0);
        unsigned long long m1 = __ballot(win1);
        const float C = 6.28318530717958647692f / 1024.0f;
        const size_t sb = (size_t)pair * 32;
        if (win0) {
            int slot = __popcll(m0 & lt);
            int k = 1023 - (int)(c0 & 1023ULL);
            float2 sp = spec_f[k];
            float ph = atan2f(sp.y, sp.x);
            double key = __longlong_as_double(
                (long long)(c0 ^ 0x8000000000000000ULL));
            double amp = sqrt(key);
            float aout = (float)(2.0 * amp / (1024.0 + 1e-8));
            float tkc = __cosf((float)k * C);
            sel[sb + slot] = make_float4(aout, ph, (float)k, tkc);
        }
        if (win1) {
            int slot = __popcll(m0) + __popcll(m1 & lt);
            int k = 1023 - (int)(c1 & 1023ULL);
            float2 sp = spec_f[k];
            float ph = atan2f(sp.y, sp.x);
            double key = __longlong_as_double(
                (long long)(c1 ^ 0x8000000000000000ULL));
            double amp = sqrt(key);
            float aout = (float)(2.0 * amp / (1024.0 + 1e-8));
            float tkc = __cosf((float)k * C);
            sel[sb + slot] = make_float4(aout, ph, (float)k, tkc);
        }
    }
}

// ---------------------------------------------------------------------------
// K3: Chebyshev reconstruction + t-periodicity (r11-proven).
// ---------------------------------------------------------------------------
__global__ __launch_bounds__(256) void recon_kernel(const float4* __restrict__ sel,
                                                    const float2* __restrict__ stats,
                                                    float* __restrict__ out) {
    __shared__ float4 sel_s[32][65];
    __shared__ float2 st_s[64];
    const int bid   = blockIdx.x;
    const int chunk = bid & 15;
    const int dt    = (bid >> 4) & 7;
    const int b     = bid >> 7;
    const int d0    = dt * 64;
    const int tid   = threadIdx.x;
#pragma unroll
    for (int it = 0; it < 8; ++it) {
        int i   = tid + it * 256;
        int j   = i & 31;
        int dls = i >> 5;
        sel_s[j][dls] = sel[((size_t)(b * D_DIM + d0 + dls)) * 32 + j];
    }
    if (tid < 64) st_s[tid] = stats[b * D_DIM + d0 + tid];
    __syncthreads();

    const int dl    = tid & 63;
    const int wvv   = tid >> 6;
    const int tbase = chunk * 64 + wvv * 16;

    float acc[16];
#pragma unroll
    for (int j = 0; j < 16; ++j) acc[j] = 0.0f;

    const float C = 6.28318530717958647692f / 1024.0f;
#pragma unroll 2
    for (int js = 0; js < 32; ++js) {
        float4 tr = sel_s[js][dl];
        const float a = tr.x;
        int k = (int)tr.z;
        float ck = tr.w;
        float sk = sqrtf(fmaxf(1.0f - ck * ck, 0.0f));
        int mm0 = (k * tbase) & 1023;
        float ang0 = fmaf((float)mm0, C, tr.y);
        float s0, c0;
        __sincosf(ang0, &s0, &c0);
        float c1 = c0 * ck - s0 * sk;
        float K2 = ck + ck;
        acc[0] = fmaf(a, c0, acc[0]);
        acc[1] = fmaf(a, c1, acc[1]);
#pragma unroll
        for (int j = 2; j < 16; ++j) {
            float c2 = fmaf(K2, c1, -c0);
            acc[j] = fmaf(a, c2, acc[j]);
            c0 = c1; c1 = c2;
        }
    }
    const float2 st = st_s[dl];
#pragma unroll
    for (int j = 0; j < 16; ++j) {
        float o = fmaf(acc[j], st.y, st.x);
        int t = tbase + j;
        out[((size_t)b * T_OUT + t) * D_DIM + d0 + dl] = o;
        if (t < 256)
            out[((size_t)b * T_OUT + t + 1024) * D_DIM + d0 + dl] = o;
    }
}

// ---------------------------------------------------------------------------
extern "C" void kernel_launch(void* const* d_in, const int* in_sizes, int n_in,
                              void* d_out, int out_size, void* d_ws, size_t ws_size,
                              hipStream_t stream) {
    const float* x = (const float*)d_in[0];
    float* out = (float*)d_out;
    char* ws = (char*)d_ws;
    const size_t MB = 1024 * 1024;

    float*   xt    = (float*)ws;                          // 16 MB
    double2* tw    = (double2*)(ws + 16 * MB);            // 16 KB
    float2*  tw16f = (float2*)(ws + 16 * MB + 65536);     // 520 B
    float2*  w32f  = (float2*)(ws + 16 * MB + 69632);     // 256 B
    float2*  stats = (float2*)(ws + 16 * MB + 73728);     // 32 KB
    int*     flag  = (int*)(ws + 16 * MB + 106496);       // 16 KB
    float4*  sel   = (float4*)(ws + 16 * MB + 131072);    //  2 MB

    transpose_kernel<<<dim3(8, 16, 8), 256, 0, stream>>>(x, xt, tw, tw16f, w32f);
    dft32_kernel<<<NPAIR, 256, 0, stream>>>(xt, tw16f, w32f, stats, sel, flag);
    dft64_kernel<<<NPAIR, 256, 0, stream>>>(xt, tw, stats, sel, flag);
    recon_kernel<<<1024, 256, 0, stream>>>(sel, stats, out);
}

// Round 22
// 67.077 us; speedup vs baseline: 1.1220x; 1.1220x over previous
//
#include <hip/hip_runtime.h>

#define T_IN 1024
#define D_DIM 512
#define T_OUT 1280
#define NPAIR 4096   // 8 * 512

// ---------------------------------------------------------------------------
// K1: transpose (b, t, d) -> (b, d, t), 64x64 LDS tiles.
// Also builds fp64 twiddles tw[m] = (cos, -sin)(2 pi m/1024), m=0..1023.
// ---------------------------------------------------------------------------
__global__ __launch_bounds__(256) void transpose_kernel(const float* __restrict__ x,
                                                        float* __restrict__ xt,
                                                        double2* __restrict__ tw) {
    __shared__ float tile[64][65];
    const int b  = blockIdx.z;
    const int t0 = blockIdx.y * 64;
    const int d0 = blockIdx.x * 64;
    const int dl = threadIdx.x & 63;
    const int r0 = threadIdx.x >> 6;   // 0..3

    if (blockIdx.x < 4 && blockIdx.y == 0 && blockIdx.z == 0) {
        int m = blockIdx.x * 256 + threadIdx.x;
        double th = (6.283185307179586476925286766559 / 1024.0) * (double)m;
        tw[m] = make_double2(cos(th), -sin(th));
    }

#pragma unroll
    for (int i = 0; i < 16; ++i) {
        int tl = r0 * 16 + i;
        tile[tl][dl] = x[((size_t)b * T_IN + (t0 + tl)) * D_DIM + d0 + dl];
    }
    __syncthreads();
#pragma unroll
    for (int i = 0; i < 16; ++i) {
        int dl2 = r0 * 16 + i;
        xt[((size_t)b * D_DIM + (d0 + dl2)) * T_IN + t0 + dl] = tile[dl][dl2];
    }
}

// ---------------------------------------------------------------------------
// sixteenth-table twiddle lookup: e^{-2 pi i m/1024}, m in [0, 1024)
// ---------------------------------------------------------------------------
__device__ __forceinline__ double2 TW16(const double2* __restrict__ E, int m) {
    const double RS2 = 0.70710678118654752440084436210485;   // sqrt(2)/2
    int r = m & 255;
    int q = (m >> 8) & 3;
    int r2 = (r <= 128) ? r : 256 - r;
    double cc, ss;
    if (r2 <= 64) {
        double2 t = E[r2];
        cc = t.x; ss = t.y;
    } else {
        double2 t = E[128 - r2];
        cc = (t.x + t.y) * RS2;
        ss = (t.x - t.y) * RS2;
    }
    double c, s;
    if (r > 128) { c = ss; s = cc; } else { c = cc; s = ss; }
    double C, S;
    switch (q) {
        case 0:  C = c;  S = s;  break;
        case 1:  C = -s; S = c;  break;
        case 2:  C = -c; S = -s; break;
        default: C = s;  S = -c; break;
    }
    return make_double2(C, -S);
}

// ---------------------------------------------------------------------------
// K2 (fused): per (b,d): stats -> standardize/clip -> even/odd butterfly ->
// 1024-pt real DFT (fp64, fold-at-write stage 2) -> hierarchical top-32 via
// 32-bit-projected radix-2 ballot descend with exact tie-fallback
// (phase A per-wave, phase B wave 0) -> write sel.
// sel = (amp, phi, k, cos(2 pi k/1024))
// ---------------------------------------------------------------------------
__global__ __launch_bounds__(256) void dft_kernel(const float* __restrict__ xt,
                                                  const double2* __restrict__ twg,
                                                  float2* __restrict__ stats,
                                                  float4* __restrict__ sel) {
    __shared__ double2 uni[1024];       // A: xs (1024 dbl); B: E+/E- [32][32];
                                        // C: spec float2[512] + cand[128] @8K
    __shared__ double2 tw_s[65];        // sixteenth table E[0..64]
    __shared__ double  red_s[16];
    double* xs_s = (double*)uni;

    const int tid  = threadIdx.x;
    const int pair = blockIdx.x;

    const float4 v = reinterpret_cast<const float4*>(xt + (size_t)pair * T_IN)[tid];

    if (tid < 65) {
        double2 t = twg[tid];                 // (cos, -sin)
        tw_s[tid] = make_double2(t.x, -t.y);  // store (cos, +sin)
    }

    // --- stats (fp64, deterministic tree reduce; final sum redundant per-thread) ---
    double sum = (double)v.x + (double)v.y + (double)v.z + (double)v.w;
    double sq  = (double)v.x * v.x + (double)v.y * v.y +
                 (double)v.z * v.z + (double)v.w * v.w;
#pragma unroll
    for (int off = 32; off; off >>= 1) {
        sum += __shfl_down(sum, off);
        sq  += __shfl_down(sq, off);
    }
    const int wv   = tid >> 6;
    const int lane = tid & 63;
    if (lane == 0) { red_s[wv] = sum; red_s[8 + wv] = sq; }
    __syncthreads();
    double mean, stdp;
    {
        double s = red_s[0] + red_s[1] + red_s[2] + red_s[3];
        double q = red_s[8] + red_s[9] + red_s[10] + red_s[11];
        mean = s * (1.0 / 1024.0);
        double var = (q - 1024.0 * mean * mean) * (1.0 / 1023.0);
        var = var > 0.0 ? var : 0.0;
        stdp = sqrt(var) + 1e-8;   // reference: std + 1e-8
        if (tid == 0) stats[pair] = make_float2((float)mean, (float)stdp);
    }
    const double inv = 1.0 / stdp;
    {
        double z0 = ((double)v.x - mean) * inv;
        double z1 = ((double)v.y - mean) * inv;
        double z2 = ((double)v.z - mean) * inv;
        double z3 = ((double)v.w - mean) * inv;
        z0 = fmin(2.0, fmax(-2.0, z0)) + 1e-9;
        z1 = fmin(2.0, fmax(-2.0, z1)) + 1e-9;
        z2 = fmin(2.0, fmax(-2.0, z2)) + 1e-9;
        z3 = fmin(2.0, fmax(-2.0, z3)) + 1e-9;
        xs_s[tid * 4 + 0] = z0;
        xs_s[tid * 4 + 1] = z1;
        xs_s[tid * 4 + 2] = z2;
        xs_s[tid * 4 + 3] = z3;
    }
    __syncthreads();

    // --- in-place even/odd butterfly over t1 (pairs t1 <-> 32-t1, t1=1..15) ---
    {
        int idx = tid;
#pragma unroll
        for (int rr = 0; rr < 2; ++rr) {
            if (idx < 480) {
                int t1p = 1 + (idx >> 5);
                int t2c = idx & 31;
                int ia = t1p * 32 + t2c;
                int ib = (32 - t1p) * 32 + t2c;
                double a = xs_s[ia], b = xs_s[ib];
                xs_s[ia] = a + b;
                xs_s[ib] = a - b;
            }
            idx += 256;
        }
    }
    __syncthreads();

    const int k1 = tid & 31;
    const int g  = tid >> 5;   // 0..7

    // --- stage 1 (into registers) ---
    double2 R0, R1, R2, R3;
    {
        const double2 w = TW16(tw_s, k1 * 32);   // e^{-2 pi i k1/32}
        const double sgn16 = (k1 & 1) ? -1.0 : 1.0;

        double ar0 = xs_s[g]      + sgn16 * xs_s[512 + g];
        double ar1 = xs_s[g + 8]  + sgn16 * xs_s[512 + g + 8];
        double ar2 = xs_s[g + 16] + sgn16 * xs_s[512 + g + 16];
        double ar3 = xs_s[g + 24] + sgn16 * xs_s[512 + g + 24];
        double ai0 = 0, ai1 = 0, ai2 = 0, ai3 = 0;

        double c = w.x, s = w.y;   // t1 = 1
#pragma unroll 5
        for (int t1 = 1; t1 <= 15; ++t1) {
            const double* eb = &xs_s[t1 * 32];
            const double* ob = &xs_s[(32 - t1) * 32];
            ar0 = fma(eb[g], c, ar0);      ai0 = fma(ob[g], s, ai0);
            ar1 = fma(eb[g + 8], c, ar1);  ai1 = fma(ob[g + 8], s, ai1);
            ar2 = fma(eb[g + 16], c, ar2); ai2 = fma(ob[g + 16], s, ai2);
            ar3 = fma(eb[g + 24], c, ar3); ai3 = fma(ob[g + 24], s, ai3);
            double cn = c * w.x - s * w.y;
            double sn = s * w.x + c * w.y;
            c = cn; s = sn;
        }
        {
            double2 tm = TW16(tw_s, g * k1);
            R0 = make_double2(ar0 * tm.x - ai0 * tm.y, ar0 * tm.y + ai0 * tm.x);
        }
        {
            double2 tm = TW16(tw_s, (g + 8) * k1);
            R1 = make_double2(ar1 * tm.x - ai1 * tm.y, ar1 * tm.y + ai1 * tm.x);
        }
        {
            double2 tm = TW16(tw_s, (g + 16) * k1);
            R2 = make_double2(ar2 * tm.x - ai2 * tm.y, ar2 * tm.y + ai2 * tm.x);
        }
        {
            double2 tm = TW16(tw_s, (g + 24) * k1);
            R3 = make_double2(ar3 * tm.x - ai3 * tm.y, ar3 * tm.y + ai3 * tm.x);
        }
    }
    __syncthreads();   // xs reads done -> overwrite union with E+/E-

    // fold-at-write: E+[t2] = S[t2] + S[t2+16] rows 0..15, E- rows 16..31.
    uni[g * 32 + k1]        = make_double2(R0.x + R2.x, R0.y + R2.y);
    uni[(g + 16) * 32 + k1] = make_double2(R0.x - R2.x, R0.y - R2.y);
    uni[(g + 8) * 32 + k1]  = make_double2(R1.x + R3.x, R1.y + R3.y);
    uni[(g + 24) * 32 + k1] = make_double2(R1.x - R3.x, R1.y - R3.y);
    __syncthreads();

    // --- stage 2: bins k2 = g (A) and g+8 (B) share parity; use E(parity of g).
    //     W32^{t2(g+8)} = W32^{t2 g} * (-i)^{t2}.
    double Ar = 0, Ai = 0, Br = 0, Bi = 0;
    {
        const double2 wa = TW16(tw_s, 32 * g);   // e^{-2 pi i g/32}
        const int ebase = (g & 1) ? 16 * 32 : 0;   // E- rows for odd g
        double ca = 1.0, sa = 0.0;
#pragma unroll
        for (int u = 0; u < 4; ++u) {
            {
                double2 E = uni[ebase + (4 * u + 0) * 32 + k1];
                double P = fma(E.x, ca, -(E.y * sa));
                double Q = fma(E.x, sa,  (E.y * ca));
                Ar += P; Ai += Q; Br += P; Bi += Q;
                double cn = fma(ca, wa.x, -(sa * wa.y));
                double sn = fma(sa, wa.x,  (ca * wa.y));
                ca = cn; sa = sn;
            }
            {
                double2 E = uni[ebase + (4 * u + 1) * 32 + k1];
                double P = fma(E.x, ca, -(E.y * sa));
                double Q = fma(E.x, sa,  (E.y * ca));
                Ar += P; Ai += Q; Br += Q; Bi -= P;
                double cn = fma(ca, wa.x, -(sa * wa.y));
                double sn = fma(sa, wa.x,  (ca * wa.y));
                ca = cn; sa = sn;
            }
            {
                double2 E = uni[ebase + (4 * u + 2) * 32 + k1];
                double P = fma(E.x, ca, -(E.y * sa));
                double Q = fma(E.x, sa,  (E.y * ca));
                Ar += P; Ai += Q; Br -= P; Bi -= Q;
                double cn = fma(ca, wa.x, -(sa * wa.y));
                double sn = fma(sa, wa.x,  (ca * wa.y));
                ca = cn; sa = sn;
            }
            {
                double2 E = uni[ebase + (4 * u + 3) * 32 + k1];
                double P = fma(E.x, ca, -(E.y * sa));
                double Q = fma(E.x, sa,  (E.y * ca));
                Ar += P; Ai += Q; Br -= Q; Bi += P;
                double cn = fma(ca, wa.x, -(sa * wa.y));
                double sn = fma(sa, wa.x,  (ca * wa.y));
                ca = cn; sa = sn;
            }
        }
    }
    const int ka = k1 + 32 * g;          // == tid
    const int kb = ka + 256;

    // amp^2 keys, (1023-k) packed in low 10 mantissa bits (lax.top_k tiebreak),
    // mapped monotonically to uint64.
    unsigned long long uA, uB;
    {
        double a2a = Ar * Ar + Ai * Ai;
        double a2b = Br * Br + Bi * Bi;
        unsigned long long bba = __double_as_longlong(a2a);
        unsigned long long bbb = __double_as_longlong(a2b);
        double keya = __longlong_as_double((bba & ~1023ULL) |
                                           (unsigned long long)(1023 - ka));
        double keyb = __longlong_as_double((bbb & ~1023ULL) |
                                           (unsigned long long)(1023 - kb));
        if (ka == 0) keya = -1.0;   // DC excluded
        unsigned long long a = (unsigned long long)__double_as_longlong(keya);
        unsigned long long b = (unsigned long long)__double_as_longlong(keyb);
        uA = a ^ ((a >> 63) ? 0xFFFFFFFFFFFFFFFFULL : 0x8000000000000000ULL);
        uB = b ^ ((b >> 63) ? 0xFFFFFFFFFFFFFFFFULL : 0x8000000000000000ULL);
    }

    // park spec (float2) in LDS bytes [0,4K); cand (double[128]) at bytes [8K,9K)
    __syncthreads();   // stage-2 LDS reads complete
    float2* spec_f = (float2*)uni;
    double* cand   = (double*)(uni + 512);
    spec_f[ka] = make_float2((float)Ar, (float)Ai);
    spec_f[kb] = make_float2((float)Br, (float)Bi);

    const unsigned long long lt = lane ? (0xFFFFFFFFFFFFFFFFULL >> (64 - lane))
                                       : 0ULL;

    // --- phase A: per-wave top-32 of its 128 keys.
    // 32-bit projected radix-2 descend (bit 63 statically 1 for non-DC keys),
    // exact tie-fallback on the low 32 bits (wave-uniform, ~never taken).
    {
        const unsigned int aHi = (unsigned int)(uA >> 32);
        const unsigned int bHi = (unsigned int)(uB >> 32);
        unsigned int pref = 0x80000000u;
#pragma unroll
        for (int bit = 30; bit >= 0; --bit) {
            unsigned int trial = pref | (1u << bit);
            int cnt = __popcll(__ballot(aHi >= trial)) +
                      __popcll(__ballot(bHi >= trial));
            if (cnt >= 32) pref = trial;
        }
        unsigned long long gA = __ballot(aHi > pref);
        unsigned long long gB = __ballot(bHi > pref);
        unsigned long long eA = __ballot(aHi == pref);
        unsigned long long eB = __ballot(bHi == pref);
        int nH = __popcll(gA) + __popcll(gB);
        int nE = __popcll(eA) + __popcll(eB);
        bool winA, winB;
        if (nH + nE == 32) {
            winA = (aHi >= pref);
            winB = (bHi >= pref);
        } else {   // tie in top-32 bits: resolve exactly on low 32 bits
            const unsigned int aLo = (unsigned int)uA;
            const unsigned int bLo = (unsigned int)uB;
            int need = 32 - nH;
            unsigned int lp = 0;
            for (int bit = 31; bit >= 0; --bit) {
                unsigned int t = lp | (1u << bit);
                int c = __popcll(__ballot((aHi == pref) && (aLo >= t))) +
                        __popcll(__ballot((bHi == pref) && (bLo >= t)));
                if (c >= need) lp = t;
            }
            winA = (aHi > pref) || ((aHi == pref) && (aLo >= lp));
            winB = (bHi > pref) || ((bHi == pref) && (bLo >= lp));
        }
        unsigned long long mA = __ballot(winA);
        unsigned long long mB = __ballot(winB);
        const int bs = wv * 32;
        if (winA)
            cand[bs + __popcll(mA & lt)] = __longlong_as_double((long long)uA);
        if (winB)
            cand[bs + __popcll(mA) + __popcll(mB & lt)] =
                __longlong_as_double((long long)uB);
    }
    __syncthreads();

    // --- phase B: wave 0 selects global top-32 from 128 candidates ---
    if (tid < 64) {
        unsigned long long c0 =
            (unsigned long long)__double_as_longlong(cand[tid]);
        unsigned long long c1 =
            (unsigned long long)__double_as_longlong(cand[tid + 64]);
        const unsigned int h0 = (unsigned int)(c0 >> 32);
        const unsigned int h1 = (unsigned int)(c1 >> 32);
        unsigned int pref = 0x80000000u;
#pragma unroll
        for (int bit = 30; bit >= 0; --bit) {
            unsigned int trial = pref | (1u << bit);
            int cnt = __popcll(__ballot(h0 >= trial)) +
                      __popcll(__ballot(h1 >= trial));
            if (cnt >= 32) pref = trial;
        }
        unsigned long long g0 = __ballot(h0 > pref);
        unsigned long long g1 = __ballot(h1 > pref);
        unsigned long long e0 = __ballot(h0 == pref);
        unsigned long long e1 = __ballot(h1 == pref);
        int nH = __popcll(g0) + __popcll(g1);
        int nE = __popcll(e0) + __popcll(e1);
        bool win0, win1;
        if (nH + nE == 32) {
            win0 = (h0 >= pref);
            win1 = (h1 >= pref);
        } else {
            const unsigned int l0 = (unsigned int)c0;
            const unsigned int l1 = (unsigned int)c1;
            int need = 32 - nH;
            unsigned int lp = 0;
            for (int bit = 31; bit >= 0; --bit) {
                unsigned int t = lp | (1u << bit);
                int c = __popcll(__ballot((h0 == pref) && (l0 >= t))) +
                        __popcll(__ballot((h1 == pref) && (l1 >= t)));
                if (c >= need) lp = t;
            }
            win0 = (h0 > pref) || ((h0 == pref) && (l0 >= lp));
            win1 = (h1 > pref) || ((h1 == pref) && (l1 >= lp));
        }
        unsigned long long m0 = __ballot(win0);
        unsigned long long m1 = __ballot(win1);
        const float C = 6.28318530717958647692f / 1024.0f;
        const size_t sb = (size_t)pair * 32;
        if (win0) {
            int slot = __popcll(m0 & lt);
            int k = 1023 - (int)(c0 & 1023ULL);
            float2 sp = spec_f[k];
            float ph = atan2f(sp.y, sp.x);
            double key = __longlong_as_double(
                (long long)(c0 ^ 0x8000000000000000ULL));
            double amp = sqrt(key);
            float aout = (float)(2.0 * amp / (1024.0 + 1e-8));
            float tkc = __cosf((float)k * C);
            sel[sb + slot] = make_float4(aout, ph, (float)k, tkc);
        }
        if (win1) {
            int slot = __popcll(m0) + __popcll(m1 & lt);
            int k = 1023 - (int)(c1 & 1023ULL);
            float2 sp = spec_f[k];
            float ph = atan2f(sp.y, sp.x);
            double key = __longlong_as_double(
                (long long)(c1 ^ 0x8000000000000000ULL));
            double amp = sqrt(key);
            float aout = (float)(2.0 * amp / (1024.0 + 1e-8));
            float tkc = __cosf((float)k * C);
            sel[sb + slot] = make_float4(aout, ph, (float)k, tkc);
        }
    }
}

// ---------------------------------------------------------------------------
// K3: Chebyshev reconstruction + t-periodicity (r11-proven).
// cos(ang0 + n*kC) via c_{n+1} = 2cos(kC)*c_n - c_{n-1}: 2 fma/term.
// out[t+1024] = out[t] for t<256 (angle periodic mod 2pi, exact).
// ---------------------------------------------------------------------------
__global__ __launch_bounds__(256) void recon_kernel(const float4* __restrict__ sel,
                                                    const float2* __restrict__ stats,
                                                    float* __restrict__ out) {
    __shared__ float4 sel_s[32][65];
    __shared__ float2 st_s[64];
    const int bid   = blockIdx.x;
    const int chunk = bid & 15;        // 16 chunks x 64 t
    const int dt    = (bid >> 4) & 7;
    const int b     = bid >> 7;
    const int d0    = dt * 64;
    const int tid   = threadIdx.x;
#pragma unroll
    for (int it = 0; it < 8; ++it) {
        int i   = tid + it * 256;
        int j   = i & 31;
        int dls = i >> 5;
        sel_s[j][dls] = sel[((size_t)(b * D_DIM + d0 + dls)) * 32 + j];
    }
    if (tid < 64) st_s[tid] = stats[b * D_DIM + d0 + tid];
    __syncthreads();

    const int dl    = tid & 63;
    const int wvv   = tid >> 6;
    const int tbase = chunk * 64 + wvv * 16;   // < 1024

    float acc[16];
#pragma unroll
    for (int j = 0; j < 16; ++j) acc[j] = 0.0f;

    const float C = 6.28318530717958647692f / 1024.0f;
#pragma unroll 2
    for (int js = 0; js < 32; ++js) {
        float4 tr = sel_s[js][dl];       // (a, phi, k, cos(kC))
        const float a = tr.x;
        int k = (int)tr.z;
        float ck = tr.w;
        float sk = sqrtf(fmaxf(1.0f - ck * ck, 0.0f));   // k in [1,511] -> sin>0
        int mm0 = (k * tbase) & 1023;
        float ang0 = fmaf((float)mm0, C, tr.y);
        float s0, c0;
        __sincosf(ang0, &s0, &c0);
        float c1 = c0 * ck - s0 * sk;
        float K2 = ck + ck;
        acc[0] = fmaf(a, c0, acc[0]);
        acc[1] = fmaf(a, c1, acc[1]);
#pragma unroll
        for (int j = 2; j < 16; ++j) {
            float c2 = fmaf(K2, c1, -c0);
            acc[j] = fmaf(a, c2, acc[j]);
            c0 = c1; c1 = c2;
        }
    }
    const float2 st = st_s[dl];
#pragma unroll
    for (int j = 0; j < 16; ++j) {
        float o = fmaf(acc[j], st.y, st.x);
        int t = tbase + j;
        out[((size_t)b * T_OUT + t) * D_DIM + d0 + dl] = o;
        if (t < 256)
            out[((size_t)b * T_OUT + t + 1024) * D_DIM + d0 + dl] = o;
    }
}

// ---------------------------------------------------------------------------
extern "C" void kernel_launch(void* const* d_in, const int* in_sizes, int n_in,
                              void* d_out, int out_size, void* d_ws, size_t ws_size,
                              hipStream_t stream) {
    const float* x = (const float*)d_in[0];
    float* out = (float*)d_out;
    char* ws = (char*)d_ws;
    const size_t MB = 1024 * 1024;

    // layout (total ~18.2 MB):
    float*   xt    = (float*)ws;                          // 16 MB
    double2* tw    = (double2*)(ws + 16 * MB);            // 16 KB
    float2*  stats = (float2*)(ws + 16 * MB + 65536);     // 32 KB
    float4*  sel   = (float4*)(ws + 16 * MB + 131072);    //  2 MB

    transpose_kernel<<<dim3(8, 16, 8), 256, 0, stream>>>(x, xt, tw);
    dft_kernel<<<NPAIR, 256, 0, stream>>>(xt, tw, stats, sel);
    recon_kernel<<<1024, 256, 0, stream>>>(sel, stats, out);
}